// Round 10
// baseline (126.645 us; speedup 1.0000x reference)
//
#include <hip/hip_runtime.h>

#define NAG 16
#define SPB 4        // scenes per block, one M=64 batch, single pass
#define NBLK 2048
#define TPB 512      // 8 waves: n-sliced 8-ways for 2x waves/CU at same LDS
#define R2f 64.0f

typedef unsigned short u16;
typedef __attribute__((ext_vector_type(8))) short short8;
typedef __attribute__((ext_vector_type(4))) float f32x4;

#define MFMA(a, b, c) __builtin_amdgcn_mfma_f32_16x16x32_bf16(a, b, c, 0, 0, 0)

// ws blob offsets in u16 units (R3-proven layout)
#define OFF_B1 0        // [Wroot1;Wrel1]  K=128 N=128  S=4 T=8  (root s0..1, rel s2..3)
#define OFF_B2 16384    // [Wroot2;Wrel2]  K=256 N=128  S=8 T=8  (root s0..3, rel s4..7)
#define OFF_H1 49152    // Wh1             K=256 N=64   S=8 T=4
#define OFF_H2 65536    // Wh2             K=64  N=32   S=2 T=2
#define OFF_H3 67584    // Wh3             K=32  N=16   S=1 T=1
#define SWZ_UNITS 8512

__device__ __forceinline__ u16 f2b(float f) {            // RNE (swizzle only)
    unsigned u = __float_as_uint(f);
    unsigned r = u + 0x7FFFu + ((u >> 16) & 1u);
    return (u16)(r >> 16);
}
// fast round-to-nearest (ties up) — hot-kernel path; sub-ulp delta vs RNE
__device__ __forceinline__ unsigned rb(float f) {
    return (__float_as_uint(f) + 0x8000u) >> 16;
}
__device__ __forceinline__ unsigned pk2(float a, float b) {
    return ((__float_as_uint(a) + 0x8000u) >> 16) |
           ((__float_as_uint(b) + 0x8000u) & 0xFFFF0000u);
}

// ---------------- weight pre-swizzle: W[K][N] f32 -> fragment order bf16 -----
__global__ __launch_bounds__(256) void swizzle_w(
    const float* __restrict__ Wrel1, const float* __restrict__ Wroot1,
    const float* __restrict__ Wrel2, const float* __restrict__ Wroot2,
    const float* __restrict__ Wh1,  const float* __restrict__ Wh2,
    const float* __restrict__ Wh3,  u16* __restrict__ ws)
{
    const int u = blockIdx.x * 256 + threadIdx.x;
    if (u >= SWZ_UNITS) return;
    int v, T, N, ksplit;
    const float *W, *W2;
    u16* dst;
    if (u < 2048)      { v = u;        T = 8; N = 128; ksplit = 64;  W = Wroot1; W2 = Wrel1; dst = ws + OFF_B1 + v * 8; }
    else if (u < 6144) { v = u - 2048; T = 8; N = 128; ksplit = 128; W = Wroot2; W2 = Wrel2; dst = ws + OFF_B2 + v * 8; }
    else if (u < 8192) { v = u - 6144; T = 4; N = 64;  ksplit = 1 << 30; W = Wh1; W2 = Wh1; dst = ws + OFF_H1 + v * 8; }
    else if (u < 8448) { v = u - 8192; T = 2; N = 32;  ksplit = 1 << 30; W = Wh2; W2 = Wh2; dst = ws + OFF_H2 + v * 8; }
    else               { v = u - 8448; T = 1; N = 16;  ksplit = 1 << 30; W = Wh3; W2 = Wh3; dst = ws + OFF_H3 + v * 8; }
    const int lane = v & 63;
    const int t = (v >> 6) % T;
    const int s = (v >> 6) / T;
    const int n = t * 16 + (lane & 15);
    const int k0 = s * 32 + (lane >> 4) * 8;
    #pragma unroll
    for (int j = 0; j < 8; ++j) {
        const int k = k0 + j;
        const float val = (k < ksplit) ? W[k * N + n] : W2[(k - ksplit) * N + n];
        dst[j] = f2b(val);
    }
}

__device__ __forceinline__ short8 ldfrag(const u16* __restrict__ ws, int off,
                                         int T, int s, int tile, int lane) {
    return *(const short8*)(ws + off + (size_t)(((s * T + tile) * 64 + lane) * 8));
}

// adjacency A-fragment, scene g packed in 32-row K window (2 scenes):
// A[m=lane&15][k=q*8+j]; valid only in this scene's half (q>>1 == odd).
__device__ __forceinline__ short8 make_adjA(unsigned m, int q, int odd) {
    union { short8 v; unsigned u[4]; } r;
    const bool on = (q >> 1) == odd;
    const int base = (q & 1) * 8;
    #pragma unroll
    for (int jj = 0; jj < 4; ++jj) {
        const int k0 = base + 2 * jj;
        const unsigned lo = (on && ((m >> k0) & 1u)) ? 0x3F80u : 0u;
        const unsigned hi = (on && ((m >> (k0 + 1)) & 1u)) ? 0x3F80u : 0u;
        r.u[jj] = lo | (hi << 16);
    }
    return r.v;
}

// LDS (u16 units): xb [64][136] (x cols0..63; later x2 cols0..127)   0..8704
//                  yT [128][72] (y^T ch-major; later h1 [64][72])    8704..17920
//                  x1b [64][136] (x1; later h2 [64][40])             17920..26624
// 53 KB -> 3 blocks/CU x 8 waves = 24 waves/CU (R9 had 12 at same LDS).
__global__ __launch_bounds__(TPB) void gnn_fused6(
    const float* __restrict__ x, const float* __restrict__ pos,
    const float* __restrict__ brel1, const float* __restrict__ brel2,
    const float* __restrict__ bh1,  const float* __restrict__ bh2,
    const float* __restrict__ bh3,
    const u16* __restrict__ ws, float* __restrict__ out)
{
    __shared__ __align__(16) u16 pool[26624];
    __shared__ unsigned mask[64];
    u16* const xb  = pool;          // also x2
    u16* const yT  = pool + 8704;   // also h1
    u16* const x1b = pool + 17920;  // also h2

    const int t = threadIdx.x;
    const int wv = t >> 6, lane = t & 63, ln = lane & 15, q = lane >> 4;
    const int c0 = 16 * wv;                 // wave's single 16-ch n-tile (L1/L2)
    const size_t sA = (size_t)blockIdx.x * SPB;

    // ---- S0: stage x (f32->bf16) + adjacency masks ----
    {
        const int r = t >> 3, co = (t & 7) * 8;
        const float* src = x + (sA * 16 + r) * 64 + co;
        const float4 v0 = *(const float4*)(src);
        const float4 v1 = *(const float4*)(src + 4);
        uint4 ua;
        ua.x = pk2(v0.x, v0.y); ua.y = pk2(v0.z, v0.w);
        ua.z = pk2(v1.x, v1.y); ua.w = pk2(v1.z, v1.w);
        *(uint4*)&xb[r * 136 + co] = ua;
    }
    if (t < 64) {
        const int g = t >> 4, a = t & 15;
        const float* pp = pos + (sA + g) * (NAG * 2);
        const float ax = pp[2 * a], ay = pp[2 * a + 1];
        unsigned m = 0;
        for (int j = 0; j < NAG; ++j) {
            const float dx = ax - pp[2 * j], dy = ay - pp[2 * j + 1];
            if (dx * dx + dy * dy <= R2f && j != a) m |= (1u << j);
        }
        mask[g * 16 + a] = m;
    }
    __syncthreads();

    short8 adjA[4];
    #pragma unroll
    for (int g = 0; g < 4; ++g) adjA[g] = make_adjA(mask[g * 16 + ln], q, g & 1);

    // ---- L1: x1 = relu(adj@(x@Wrel1) + x@Wroot1 + b1) -> x1b ----
    {
        short8 Brl[2], Bro[2], Af[4][2];
        #pragma unroll
        for (int s = 0; s < 2; ++s) {
            Brl[s] = ldfrag(ws, OFF_B1, 8, s + 2, wv, lane);
            Bro[s] = ldfrag(ws, OFF_B1, 8, s, wv, lane);
        }
        #pragma unroll
        for (int m = 0; m < 4; ++m) {               // y1 -> yT (no relu, no bias)
            Af[m][0] = *(const short8*)&xb[(m * 16 + ln) * 136 + q * 8];
            Af[m][1] = *(const short8*)&xb[(m * 16 + ln) * 136 + 32 + q * 8];
            f32x4 a0 = {0.f, 0.f, 0.f, 0.f};
            a0 = MFMA(Af[m][0], Brl[0], a0);
            a0 = MFMA(Af[m][1], Brl[1], a0);
            uint2 u0; u0.x = pk2(a0[0], a0[1]); u0.y = pk2(a0[2], a0[3]);
            *(uint2*)&yT[(c0 + ln) * 72 + m * 16 + q * 4] = u0;
        }
        short8 By[2];
        #pragma unroll
        for (int w = 0; w < 2; ++w)                 // wave-local readback
            By[w] = *(const short8*)&yT[(c0 + ln) * 72 + w * 32 + q * 8];
        const float b0 = brel1[c0 + ln];
        #pragma unroll
        for (int g = 0; g < 4; ++g) {
            f32x4 a0 = {b0, b0, b0, b0};
            a0 = MFMA(Af[g][0], Bro[0], a0);
            a0 = MFMA(Af[g][1], Bro[1], a0);
            a0 = MFMA(adjA[g], By[g >> 1], a0);
            #pragma unroll
            for (int r = 0; r < 4; ++r)
                x1b[(g * 16 + q * 4 + r) * 136 + c0 + ln] = (u16)rb(fmaxf(a0[r], 0.f));
        }
    }
    __syncthreads();

    // ---- L2: x2 = relu(adj@(x1@Wrel2) + x1@Wroot2 + b2) -> xb (x dead) ----
    {
        short8 Brl[4];
        #pragma unroll
        for (int s = 0; s < 4; ++s) Brl[s] = ldfrag(ws, OFF_B2, 8, s + 4, wv, lane);
        #pragma unroll
        for (int m = 0; m < 4; ++m) {               // y2 -> yT
            f32x4 a0 = {0.f, 0.f, 0.f, 0.f};
            #pragma unroll
            for (int s = 0; s < 4; ++s) {
                const short8 A = *(const short8*)&x1b[(m * 16 + ln) * 136 + s * 32 + q * 8];
                a0 = MFMA(A, Brl[s], a0);
            }
            uint2 u0; u0.x = pk2(a0[0], a0[1]); u0.y = pk2(a0[2], a0[3]);
            *(uint2*)&yT[(c0 + ln) * 72 + m * 16 + q * 4] = u0;
        }
        short8 By[2];
        #pragma unroll
        for (int w = 0; w < 2; ++w)
            By[w] = *(const short8*)&yT[(c0 + ln) * 72 + w * 32 + q * 8];
        short8 Bro[4];
        #pragma unroll
        for (int s = 0; s < 4; ++s) Bro[s] = ldfrag(ws, OFF_B2, 8, s, wv, lane);
        const float b0 = brel2[c0 + ln];
        #pragma unroll
        for (int g = 0; g < 4; ++g) {
            f32x4 a0 = {b0, b0, b0, b0};
            #pragma unroll
            for (int s = 0; s < 4; ++s) {
                const short8 A = *(const short8*)&x1b[(g * 16 + ln) * 136 + s * 32 + q * 8];
                a0 = MFMA(A, Bro[s], a0);
            }
            a0 = MFMA(adjA[g], By[g >> 1], a0);
            #pragma unroll
            for (int r = 0; r < 4; ++r)
                xb[(g * 16 + q * 4 + r) * 136 + c0 + ln] = (u16)rb(fmaxf(a0[r], 0.f));
        }
    }
    __syncthreads();

    // ---- GEMM3: h1 = relu([x1|x2] @ Wh1 + bh1); wave = (m-half, n-tile) ----
    {
        const int nt = wv & 3, mh = wv >> 2;
        short8 Bf[8];
        #pragma unroll
        for (int s = 0; s < 8; ++s) Bf[s] = ldfrag(ws, OFF_H1, 4, s, nt, lane);
        const float b = bh1[nt * 16 + ln];
        #pragma unroll
        for (int mi = 0; mi < 2; ++mi) {
            const int m = 2 * mh + mi;
            f32x4 a = {b, b, b, b}, c = {0.f, 0.f, 0.f, 0.f};
            #pragma unroll
            for (int s = 0; s < 4; ++s) {
                const short8 A1 = *(const short8*)&x1b[(m * 16 + ln) * 136 + s * 32 + q * 8];
                const short8 A2 = *(const short8*)&xb[(m * 16 + ln) * 136 + s * 32 + q * 8];
                a = MFMA(A1, Bf[s], a);
                c = MFMA(A2, Bf[s + 4], c);
            }
            #pragma unroll
            for (int r = 0; r < 4; ++r)
                yT[(m * 16 + q * 4 + r) * 72 + nt * 16 + ln] = (u16)rb(fmaxf(a[r] + c[r], 0.f));
        }
    }
    __syncthreads();

    // ---- GEMM4+5 (wave-local: waves 0..3, wave = scene): h2 then out ----
    if (wv < 4) {
        const u16* h1b = yT;
        u16* h2b = x1b;                              // x1 dead
        const short8 A0 = *(const short8*)&h1b[(wv * 16 + ln) * 72 + q * 8];
        const short8 A1 = *(const short8*)&h1b[(wv * 16 + ln) * 72 + 32 + q * 8];
        #pragma unroll
        for (int nt = 0; nt < 2; ++nt) {
            const short8 B0 = ldfrag(ws, OFF_H2, 2, 0, nt, lane);
            const short8 B1 = ldfrag(ws, OFF_H2, 2, 1, nt, lane);
            const float b = bh2[nt * 16 + ln];
            f32x4 a = {b, b, b, b};
            a = MFMA(A0, B0, a);
            a = MFMA(A1, B1, a);
            #pragma unroll
            for (int r = 0; r < 4; ++r)
                h2b[(wv * 16 + q * 4 + r) * 40 + nt * 16 + ln] = (u16)rb(fmaxf(a[r], 0.f));
        }
        const short8 A = *(const short8*)&h2b[(wv * 16 + ln) * 40 + q * 8];
        const short8 B = ldfrag(ws, OFF_H3, 1, 0, 0, lane);
        const float b = bh3[ln];
        f32x4 a = {b, b, b, b};
        a = MFMA(A, B, a);
        #pragma unroll
        for (int r = 0; r < 4; ++r)
            out[(sA * 16 + wv * 16 + q * 4 + r) * 16 + ln] = a[r];
    }
}

extern "C" void kernel_launch(void* const* d_in, const int* in_sizes, int n_in,
                              void* d_out, int out_size, void* d_ws, size_t ws_size,
                              hipStream_t stream) {
    const float* x      = (const float*)d_in[0];
    const float* pos    = (const float*)d_in[1];
    const float* Wrel1  = (const float*)d_in[2];
    const float* brel1  = (const float*)d_in[3];
    const float* Wroot1 = (const float*)d_in[4];
    const float* Wrel2  = (const float*)d_in[5];
    const float* brel2  = (const float*)d_in[6];
    const float* Wroot2 = (const float*)d_in[7];
    const float* Wh1    = (const float*)d_in[8];
    const float* bh1    = (const float*)d_in[9];
    const float* Wh2    = (const float*)d_in[10];
    const float* bh2    = (const float*)d_in[11];
    const float* Wh3    = (const float*)d_in[12];
    const float* bh3    = (const float*)d_in[13];
    u16* ws = (u16*)d_ws;

    swizzle_w<<<(SWZ_UNITS + 255) / 256, 256, 0, stream>>>(
        Wrel1, Wroot1, Wrel2, Wroot2, Wh1, Wh2, Wh3, ws);
    gnn_fused6<<<NBLK, TPB, 0, stream>>>(
        x, pos, brel1, brel2, bh1, bh2, bh3, ws, (float*)d_out);
}